// Round 1
// baseline (5358.434 us; speedup 1.0000x reference)
//
#include <hip/hip_runtime.h>

#define DIM 1536
#define NHEADS 12
#define HD 128
#define FFN 8960
#define SQ 3456
#define T5 512
#define LCTX 769
#define IMG 257
#define EPSL 1e-6f

typedef __bf16 bf16;
typedef __bf16 bf16x8 __attribute__((ext_vector_type(8)));
typedef float f32x4 __attribute__((ext_vector_type(4)));

__device__ inline bf16x8 zero_bf16x8() {
  bf16x8 v;
  for (int i = 0; i < 8; i++) v[i] = (bf16)0.0f;
  return v;
}

// ---------------- small utility kernels ----------------

__global__ void add_vec_kernel(const float* __restrict__ a, const float* __restrict__ b,
                               float* __restrict__ out, int n) {
  int i = blockIdx.x * 256 + threadIdx.x;
  if (i < n) out[i] = a[i] + b[i];
}

__global__ void cast_f32_bf16_kernel(const float* __restrict__ in, bf16* __restrict__ out, int n) {
  int i = blockIdx.x * 256 + threadIdx.x;
  if (i < n) out[i] = (bf16)in[i];
}

// transpose W (K x N, f32) -> Wt (N x K, bf16). K,N multiples of 32.
__global__ void transpose_w_kernel(const float* __restrict__ W, bf16* __restrict__ Wt,
                                   int K, int N) {
  __shared__ float tile[32][33];
  int n0 = blockIdx.x * 32, k0 = blockIdx.y * 32;
  int tx = threadIdx.x, ty = threadIdx.y;  // block (32,8)
  for (int i = ty; i < 32; i += 8)
    tile[i][tx] = W[(size_t)(k0 + i) * N + n0 + tx];
  __syncthreads();
  for (int i = ty; i < 32; i += 8)
    Wt[(size_t)(n0 + i) * K + k0 + tx] = (bf16)tile[tx][i];
}

// block=256, two-value sum reduction broadcast to all threads
__device__ inline void block_reduce2(float& s1, float& s2) {
  __shared__ float buf[8];
  for (int off = 32; off; off >>= 1) {
    s1 += __shfl_down(s1, off, 64);
    s2 += __shfl_down(s2, off, 64);
  }
  int w = threadIdx.x >> 6;
  if ((threadIdx.x & 63) == 0) { buf[w] = s1; buf[w + 4] = s2; }
  __syncthreads();
  s1 = buf[0] + buf[1] + buf[2] + buf[3];
  s2 = buf[4] + buf[5] + buf[6] + buf[7];
  __syncthreads();
}

// y = LN(x) * (gamma (+1?)) + beta ; one block per row
__global__ __launch_bounds__(256) void ln_mod_kernel(
    const float* __restrict__ X, const float* __restrict__ gamma,
    const float* __restrict__ beta, int plus_one, bf16* __restrict__ out) {
  int r = blockIdx.x;
  const float* xr = X + (size_t)r * DIM;
  float v[6], s = 0.f, s2 = 0.f;
  for (int i = 0; i < 6; i++) {
    v[i] = xr[threadIdx.x + i * 256];
    s += v[i]; s2 += v[i] * v[i];
  }
  block_reduce2(s, s2);
  float mean = s * (1.0f / DIM);
  float var = s2 * (1.0f / DIM) - mean * mean;
  float rstd = rsqrtf(var + EPSL);
  float add1 = plus_one ? 1.0f : 0.0f;
  for (int i = 0; i < 6; i++) {
    int c = threadIdx.x + i * 256;
    out[(size_t)r * DIM + c] = (bf16)(((v[i] - mean) * rstd) * (gamma[c] + add1) + beta[c]);
  }
}

// RMS-norm over 1536 (+weight), optional 3D RoPE, f32 in -> bf16 out. one block per row.
__global__ __launch_bounds__(256) void rms_rope_kernel(
    const float* __restrict__ X, const float* __restrict__ nw,
    const float* __restrict__ freqs, int do_rope, bf16* __restrict__ out) {
  int r = blockIdx.x;
  const float* xr = X + (size_t)r * DIM;
  float s2 = 0.f, dummy = 0.f;
  float v[6];
  for (int i = 0; i < 6; i++) {
    v[i] = xr[threadIdx.x + i * 256];
    s2 += v[i] * v[i];
  }
  block_reduce2(s2, dummy);
  float rms = rsqrtf(s2 * (1.0f / DIM) + EPSL);
  if (!do_rope) {
    for (int i = 0; i < 6; i++) {
      int c = threadIdx.x + i * 256;
      out[(size_t)r * DIM + c] = (bf16)(v[i] * rms * nw[c]);
    }
  } else {
    // s -> (f,h,w) with H=18, W=24
    int f = r / (18 * 24), rem = r % (18 * 24), hh = rem / 24, ww = rem % 24;
    for (int i = 0; i < 3; i++) {
      int p = threadIdx.x + i * 256;  // pair index 0..767 ; global dims 2p, 2p+1
      int id = p & 63;                 // within-head pair index (HD/2=64)
      int idx = id < 22 ? f : (id < 43 ? hh : ww);
      float th = freqs[idx * 64 + id];
      float cs = __cosf(th), sn = __sinf(th);
      float re = xr[2 * p] * rms * nw[2 * p];
      float im = xr[2 * p + 1] * rms * nw[2 * p + 1];
      out[(size_t)r * DIM + 2 * p]     = (bf16)(re * cs - im * sn);
      out[(size_t)r * DIM + 2 * p + 1] = (bf16)(re * sn + im * cs);
    }
  }
}

// ---------------- GEMM: C[M,N] = A[M,K](bf16) @ Wt[N,K](bf16)^T + epilogue ----------------
// epilogue: t = acc + bias[col]; if gelu: gelu_tanh(t); t *= scalev[col]; t += resid[row,col]
__global__ __launch_bounds__(256) void gemm_bt_kernel(
    const bf16* __restrict__ A, const bf16* __restrict__ Wt,
    const float* __restrict__ bias, const float* __restrict__ scalev,
    const float* __restrict__ resid, float* __restrict__ outF,
    bf16* __restrict__ outB, int M, int N, int K, int gelu) {
  __shared__ bf16 As[128][40];
  __shared__ bf16 Bs[128][40];
  int tid = threadIdx.x;
  int tm0 = blockIdx.y * 128, tn0 = blockIdx.x * 128;
  int lane = tid & 63, wave = tid >> 6;
  int quad = lane >> 4, l16 = lane & 15;
  int mbase = (wave >> 1) * 64, nbase = (wave & 1) * 64;
  int srow = tid >> 1, scol = (tid & 1) * 16;
  f32x4 acc[4][4];
  for (int mi = 0; mi < 4; mi++)
    for (int ni = 0; ni < 4; ni++)
      for (int rr = 0; rr < 4; rr++) acc[mi][ni][rr] = 0.0f;

  for (int k0 = 0; k0 < K; k0 += 32) {
    bf16x8 a0 = zero_bf16x8(), a1 = zero_bf16x8(), b0, b1;
    int arow = tm0 + srow;
    if (arow < M) {
      const bf16* ap = A + (size_t)arow * K + k0 + scol;
      a0 = *(const bf16x8*)ap;
      a1 = *(const bf16x8*)(ap + 8);
    }
    const bf16* bp = Wt + (size_t)(tn0 + srow) * K + k0 + scol;
    b0 = *(const bf16x8*)bp;
    b1 = *(const bf16x8*)(bp + 8);
    __syncthreads();
    *(bf16x8*)&As[srow][scol] = a0;
    *(bf16x8*)&As[srow][scol + 8] = a1;
    *(bf16x8*)&Bs[srow][scol] = b0;
    *(bf16x8*)&Bs[srow][scol + 8] = b1;
    __syncthreads();
    bf16x8 af[4], bfr[4];
    for (int mi = 0; mi < 4; mi++) af[mi] = *(bf16x8*)&As[mbase + mi * 16 + l16][quad * 8];
    for (int ni = 0; ni < 4; ni++) bfr[ni] = *(bf16x8*)&Bs[nbase + ni * 16 + l16][quad * 8];
    for (int mi = 0; mi < 4; mi++)
      for (int ni = 0; ni < 4; ni++)
        acc[mi][ni] = __builtin_amdgcn_mfma_f32_16x16x32_bf16(af[mi], bfr[ni], acc[mi][ni], 0, 0, 0);
  }

  for (int mi = 0; mi < 4; mi++) {
    int rbase = tm0 + mbase + mi * 16 + quad * 4;
    for (int ni = 0; ni < 4; ni++) {
      int col = tn0 + nbase + ni * 16 + l16;
      float b = bias ? bias[col] : 0.0f;
      float sc = scalev ? scalev[col] : 1.0f;
      for (int rr = 0; rr < 4; rr++) {
        int row = rbase + rr;
        if (row >= M) continue;
        float t = acc[mi][ni][rr] + b;
        if (gelu) {
          float z = t;
          t = 0.5f * z * (1.0f + tanhf(0.7978845608028654f * (z + 0.044715f * z * z * z)));
        }
        t *= sc;
        size_t idx = (size_t)row * N + col;
        if (resid) t += resid[idx];
        if (outF) outF[idx] = t;
        else outB[idx] = (bf16)t;
      }
    }
  }
}

// ---------------- Flash attention (bf16 MFMA, online softmax) ----------------
// Q: [SQ, 12*128] bf16 ; K/V: [L, 12*128] bf16. One block = 1 head x 64 q-rows (16/wave).
// mode: 0 = write bf16 to outB; 1 = write f32 to outF; 2 = accumulate f32 into outF.
__global__ __launch_bounds__(256) void attn_kernel(
    const bf16* __restrict__ Q, const bf16* __restrict__ Kb, const bf16* __restrict__ Vb,
    float* __restrict__ outF, bf16* __restrict__ outB, int L, int mode) {
  __shared__ bf16 Ks[32][136];
  __shared__ bf16 Vts[128][40];
  __shared__ bf16 Ps[4][16][40];
  int tid = threadIdx.x;
  int hb = blockIdx.y;
  int q0 = blockIdx.x * 64;
  int lane = tid & 63, wave = tid >> 6;
  int quad = lane >> 4, l16 = lane & 15;
  int qrow = q0 + wave * 16 + l16;

  bf16x8 qf[4];
  for (int c = 0; c < 4; c++)
    qf[c] = *(const bf16x8*)(Q + (size_t)qrow * DIM + hb * HD + c * 32 + quad * 8);

  f32x4 o[8];
  for (int ff = 0; ff < 8; ff++)
    for (int rr = 0; rr < 4; rr++) o[ff][rr] = 0.0f;
  float m_i[4], l_i[4];
  for (int r = 0; r < 4; r++) { m_i[r] = -1e30f; l_i[r] = 0.0f; }
  const float sc = 0.08838834764831845f;  // 1/sqrt(128)

  int srow = tid >> 3, scol = (tid & 7) * 16;  // stage: key row 0..31, dim 0..127
  int nt = (L + 31) / 32;
  for (int kt = 0; kt < nt; kt++) {
    __syncthreads();
    int key = kt * 32 + srow;
    bf16x8 k0v = zero_bf16x8(), k1v = zero_bf16x8();
    bf16x8 v0v = zero_bf16x8(), v1v = zero_bf16x8();
    if (key < L) {
      const bf16* kp = Kb + (size_t)key * DIM + hb * HD + scol;
      k0v = *(const bf16x8*)kp; k1v = *(const bf16x8*)(kp + 8);
      const bf16* vp = Vb + (size_t)key * DIM + hb * HD + scol;
      v0v = *(const bf16x8*)vp; v1v = *(const bf16x8*)(vp + 8);
    }
    *(bf16x8*)&Ks[srow][scol] = k0v;
    *(bf16x8*)&Ks[srow][scol + 8] = k1v;
    for (int j = 0; j < 8; j++) Vts[scol + j][srow] = v0v[j];
    for (int j = 0; j < 8; j++) Vts[scol + 8 + j][srow] = v1v[j];
    __syncthreads();

    // S = Q K^T for 16 q-rows x 32 keys
    f32x4 sfr[2];
    for (int nf = 0; nf < 2; nf++) {
      f32x4 a;
      for (int rr = 0; rr < 4; rr++) a[rr] = 0.0f;
      for (int c = 0; c < 4; c++) {
        bf16x8 kf = *(bf16x8*)&Ks[nf * 16 + l16][c * 32 + quad * 8];
        a = __builtin_amdgcn_mfma_f32_16x16x32_bf16(qf[c], kf, a, 0, 0, 0);
      }
      sfr[nf] = a;
    }
    for (int nf = 0; nf < 2; nf++) {
      int colg = kt * 32 + nf * 16 + l16;
      bool valid = colg < L;
      for (int r = 0; r < 4; r++)
        sfr[nf][r] = valid ? sfr[nf][r] * sc : -1e30f;
    }
    // online softmax (C-layout rows = quad*4+r; 16 cols spread over the quad's 16 lanes)
    float mnew[4], alpha[4];
    for (int r = 0; r < 4; r++) {
      float t = fmaxf(sfr[0][r], sfr[1][r]);
      for (int off = 1; off < 16; off <<= 1) t = fmaxf(t, __shfl_xor(t, off, 64));
      mnew[r] = fmaxf(m_i[r], t);
      alpha[r] = __expf(m_i[r] - mnew[r]);
      m_i[r] = mnew[r];
    }
    for (int r = 0; r < 4; r++) {
      float p0 = __expf(sfr[0][r] - mnew[r]);
      float p1 = __expf(sfr[1][r] - mnew[r]);
      Ps[wave][quad * 4 + r][l16] = (bf16)p0;
      Ps[wave][quad * 4 + r][16 + l16] = (bf16)p1;
      float t = p0 + p1;
      for (int off = 1; off < 16; off <<= 1) t += __shfl_xor(t, off, 64);
      l_i[r] = l_i[r] * alpha[r] + t;
      for (int ff = 0; ff < 8; ff++) o[ff][r] *= alpha[r];
    }
    __syncthreads();  // cross-lane P handoff via LDS: block compiler reorder + wave ordering
    bf16x8 pf = *(bf16x8*)&Ps[wave][l16][quad * 8];
    for (int ff = 0; ff < 8; ff++) {
      bf16x8 vf = *(bf16x8*)&Vts[ff * 16 + l16][quad * 8];
      o[ff] = __builtin_amdgcn_mfma_f32_16x16x32_bf16(pf, vf, o[ff], 0, 0, 0);
    }
  }

  for (int r = 0; r < 4; r++) {
    float inv = 1.0f / l_i[r];
    for (int ff = 0; ff < 8; ff++) o[ff][r] *= inv;
  }
  for (int ff = 0; ff < 8; ff++) {
    for (int r = 0; r < 4; r++) {
      int row = q0 + wave * 16 + quad * 4 + r;
      int col = hb * HD + ff * 16 + l16;
      size_t idx = (size_t)row * DIM + col;
      if (mode == 0) outB[idx] = (bf16)o[ff][r];
      else if (mode == 1) outF[idx] = o[ff][r];
      else outF[idx] += o[ff][r];
    }
  }
}

// ---------------- host orchestration ----------------

extern "C" void kernel_launch(void* const* d_in, const int* in_sizes, int n_in,
                              void* d_out, int out_size, void* d_ws, size_t ws_size,
                              hipStream_t stream) {
  const float* x      = (const float*)d_in[0];
  const float* e      = (const float*)d_in[1];
  const float* ctx    = (const float*)d_in[2];
  const float* freqs  = (const float*)d_in[3];
  const float* modv   = (const float*)d_in[4];
  const float* sa_qw  = (const float*)d_in[5];
  const float* sa_qb  = (const float*)d_in[6];
  const float* sa_kw  = (const float*)d_in[7];
  const float* sa_kb  = (const float*)d_in[8];
  const float* sa_vw  = (const float*)d_in[9];
  const float* sa_vb  = (const float*)d_in[10];
  const float* sa_ow  = (const float*)d_in[11];
  const float* sa_ob  = (const float*)d_in[12];
  const float* sa_nq  = (const float*)d_in[13];
  const float* sa_nk  = (const float*)d_in[14];
  const float* norm3w = (const float*)d_in[15];
  const float* norm3b = (const float*)d_in[16];
  const float* ca_qw  = (const float*)d_in[17];
  const float* ca_qb  = (const float*)d_in[18];
  const float* ca_kw  = (const float*)d_in[19];
  const float* ca_kb  = (const float*)d_in[20];
  const float* ca_vw  = (const float*)d_in[21];
  const float* ca_vb  = (const float*)d_in[22];
  const float* ca_kiw = (const float*)d_in[23];
  const float* ca_kib = (const float*)d_in[24];
  const float* ca_viw = (const float*)d_in[25];
  const float* ca_vib = (const float*)d_in[26];
  const float* ca_ow  = (const float*)d_in[27];
  const float* ca_ob  = (const float*)d_in[28];
  const float* ca_nq  = (const float*)d_in[29];
  const float* ca_nk  = (const float*)d_in[30];
  const float* ca_nki = (const float*)d_in[31];
  const float* ffn_w1 = (const float*)d_in[32];
  const float* ffn_b1 = (const float*)d_in[33];
  const float* ffn_w2 = (const float*)d_in[34];
  const float* ffn_b2 = (const float*)d_in[35];

  char* ws = (char*)d_ws;
  size_t off = 0;
  auto alloc = [&](size_t bytes) -> void* {
    void* p = ws + off;
    off += (bytes + 255) & ~(size_t)255;
    return p;
  };
  float* e6f   = (float*)alloc((size_t)6 * DIM * 4);
  bf16* act_bf = (bf16*)alloc((size_t)SQ * DIM * 2);
  bf16* q_bf   = (bf16*)alloc((size_t)SQ * DIM * 2);
  bf16* k_bf   = (bf16*)alloc((size_t)SQ * DIM * 2);
  bf16* v_bf   = (bf16*)alloc((size_t)SQ * DIM * 2);
  float* projf = (float*)alloc((size_t)SQ * DIM * 4);
  float* xcur  = (float*)alloc((size_t)SQ * DIM * 4);
  bf16* wts    = (bf16*)alloc((size_t)FFN * DIM * 2);
  bf16* y1     = (bf16*)alloc((size_t)SQ * FFN * 2);
  bf16* ctx_bf = (bf16*)alloc((size_t)LCTX * DIM * 2);
  float* ctxpf = (float*)alloc((size_t)T5 * DIM * 4);
  bf16* kt_bf  = (bf16*)alloc((size_t)T5 * DIM * 2);
  bf16* vt_bf  = (bf16*)alloc((size_t)T5 * DIM * 2);
  bf16* ki_bf  = (bf16*)alloc((size_t)IMG * DIM * 2);
  bf16* vi_bf  = (bf16*)alloc((size_t)IMG * DIM * 2);

  const float* e0 = e6f;
  const float* e1 = e6f + DIM;
  const float* e2 = e6f + 2 * DIM;
  const float* e3 = e6f + 3 * DIM;
  const float* e4 = e6f + 4 * DIM;
  const float* e5 = e6f + 5 * DIM;

  dim3 tblk(32, 8);
  dim3 tg_sq(DIM / 32, DIM / 32);          // 1536x1536 weight transpose
  dim3 gg_full(DIM / 128, SQ / 128);       // (12, 27)
  dim3 ag(SQ / 64, NHEADS);                // attention grid (54, 12)

  // e6 = modulation + e
  add_vec_kernel<<<(6 * DIM + 255) / 256, 256, 0, stream>>>(modv, e, e6f, 6 * DIM);

  // xs = LN(x)*(1+e1)+e0
  ln_mod_kernel<<<SQ, 256, 0, stream>>>(x, e1, e0, 1, act_bf);

  // ---- self attention ----
  transpose_w_kernel<<<tg_sq, tblk, 0, stream>>>(sa_qw, wts, DIM, DIM);
  gemm_bt_kernel<<<gg_full, 256, 0, stream>>>(act_bf, wts, sa_qb, nullptr, nullptr, projf, nullptr, SQ, DIM, DIM, 0);
  rms_rope_kernel<<<SQ, 256, 0, stream>>>(projf, sa_nq, freqs, 1, q_bf);

  transpose_w_kernel<<<tg_sq, tblk, 0, stream>>>(sa_kw, wts, DIM, DIM);
  gemm_bt_kernel<<<gg_full, 256, 0, stream>>>(act_bf, wts, sa_kb, nullptr, nullptr, projf, nullptr, SQ, DIM, DIM, 0);
  rms_rope_kernel<<<SQ, 256, 0, stream>>>(projf, sa_nk, freqs, 1, k_bf);

  transpose_w_kernel<<<tg_sq, tblk, 0, stream>>>(sa_vw, wts, DIM, DIM);
  gemm_bt_kernel<<<gg_full, 256, 0, stream>>>(act_bf, wts, sa_vb, nullptr, nullptr, nullptr, v_bf, SQ, DIM, DIM, 0);

  attn_kernel<<<ag, 256, 0, stream>>>(q_bf, k_bf, v_bf, nullptr, act_bf, SQ, 0);

  // x = x + (attn @ sa_ow + sa_ob) * e2
  transpose_w_kernel<<<tg_sq, tblk, 0, stream>>>(sa_ow, wts, DIM, DIM);
  gemm_bt_kernel<<<gg_full, 256, 0, stream>>>(act_bf, wts, sa_ob, e2, x, xcur, nullptr, SQ, DIM, DIM, 0);

  // ---- cross attention ----
  ln_mod_kernel<<<SQ, 256, 0, stream>>>(xcur, norm3w, norm3b, 0, act_bf);

  transpose_w_kernel<<<tg_sq, tblk, 0, stream>>>(ca_qw, wts, DIM, DIM);
  gemm_bt_kernel<<<gg_full, 256, 0, stream>>>(act_bf, wts, ca_qb, nullptr, nullptr, projf, nullptr, SQ, DIM, DIM, 0);
  rms_rope_kernel<<<SQ, 256, 0, stream>>>(projf, ca_nq, freqs, 0, q_bf);

  cast_f32_bf16_kernel<<<(LCTX * DIM + 255) / 256, 256, 0, stream>>>(ctx, ctx_bf, LCTX * DIM);

  // txt keys/values (rows 257..768 of context)
  transpose_w_kernel<<<tg_sq, tblk, 0, stream>>>(ca_kw, wts, DIM, DIM);
  gemm_bt_kernel<<<dim3(DIM / 128, T5 / 128), 256, 0, stream>>>(ctx_bf + (size_t)IMG * DIM, wts, ca_kb, nullptr, nullptr, ctxpf, nullptr, T5, DIM, DIM, 0);
  rms_rope_kernel<<<T5, 256, 0, stream>>>(ctxpf, ca_nk, freqs, 0, kt_bf);

  transpose_w_kernel<<<tg_sq, tblk, 0, stream>>>(ca_vw, wts, DIM, DIM);
  gemm_bt_kernel<<<dim3(DIM / 128, T5 / 128), 256, 0, stream>>>(ctx_bf + (size_t)IMG * DIM, wts, ca_vb, nullptr, nullptr, nullptr, vt_bf, T5, DIM, DIM, 0);

  // img keys/values (rows 0..256)
  transpose_w_kernel<<<tg_sq, tblk, 0, stream>>>(ca_kiw, wts, DIM, DIM);
  gemm_bt_kernel<<<dim3(DIM / 128, 3), 256, 0, stream>>>(ctx_bf, wts, ca_kib, nullptr, nullptr, ctxpf, nullptr, IMG, DIM, DIM, 0);
  rms_rope_kernel<<<IMG, 256, 0, stream>>>(ctxpf, ca_nki, freqs, 0, ki_bf);

  transpose_w_kernel<<<tg_sq, tblk, 0, stream>>>(ca_viw, wts, DIM, DIM);
  gemm_bt_kernel<<<dim3(DIM / 128, 3), 256, 0, stream>>>(ctx_bf, wts, ca_vib, nullptr, nullptr, nullptr, vi_bf, IMG, DIM, DIM, 0);

  attn_kernel<<<ag, 256, 0, stream>>>(q_bf, kt_bf, vt_bf, projf, nullptr, T5, 1);
  attn_kernel<<<ag, 256, 0, stream>>>(q_bf, ki_bf, vi_bf, projf, nullptr, IMG, 2);
  cast_f32_bf16_kernel<<<(SQ * DIM + 255) / 256, 256, 0, stream>>>(projf, act_bf, SQ * DIM);

  // x = x + attn2 @ ca_ow + ca_ob
  transpose_w_kernel<<<tg_sq, tblk, 0, stream>>>(ca_ow, wts, DIM, DIM);
  gemm_bt_kernel<<<gg_full, 256, 0, stream>>>(act_bf, wts, ca_ob, nullptr, xcur, xcur, nullptr, SQ, DIM, DIM, 0);

  // ---- FFN ----
  ln_mod_kernel<<<SQ, 256, 0, stream>>>(xcur, e4, e3, 1, act_bf);

  transpose_w_kernel<<<dim3(FFN / 32, DIM / 32), tblk, 0, stream>>>(ffn_w1, wts, DIM, FFN);
  gemm_bt_kernel<<<dim3(FFN / 128, SQ / 128), 256, 0, stream>>>(act_bf, wts, ffn_b1, nullptr, nullptr, nullptr, y1, SQ, FFN, DIM, 1);

  transpose_w_kernel<<<dim3(DIM / 32, FFN / 32), tblk, 0, stream>>>(ffn_w2, wts, FFN, DIM);
  gemm_bt_kernel<<<dim3(DIM / 128, SQ / 128), 256, 0, stream>>>(y1, wts, ffn_b2, e5, xcur, (float*)d_out, nullptr, SQ, DIM, FFN, 0);
}

// Round 2
// 2960.370 us; speedup vs baseline: 1.8101x; 1.8101x over previous
//
#include <hip/hip_runtime.h>

#define DIM 1536
#define NHEADS 12
#define HD 128
#define FFN 8960
#define SQ 3456
#define T5 512
#define LCTX 769
#define IMG 257
#define IMGP 384
#define EPSL 1e-6f

typedef __bf16 bf16;
typedef __bf16 bf16x8 __attribute__((ext_vector_type(8)));
typedef float f32x4 __attribute__((ext_vector_type(4)));

__device__ inline bf16x8 zero_bf16x8() {
  bf16x8 v;
  for (int i = 0; i < 8; i++) v[i] = (bf16)0.0f;
  return v;
}

// async 16B global -> LDS. lds base must be wave-uniform; lane i lands at lds + i*16.
__device__ inline void glds16(const bf16* g, bf16* lds) {
  __builtin_amdgcn_global_load_lds(
      (const __attribute__((address_space(1))) void*)g,
      (__attribute__((address_space(3))) void*)lds, 16, 0, 0);
}

// ---------------- small utility kernels ----------------

__global__ void add_vec_kernel(const float* __restrict__ a, const float* __restrict__ b,
                               float* __restrict__ out, int n) {
  int i = blockIdx.x * 256 + threadIdx.x;
  if (i < n) out[i] = a[i] + b[i];
}

__global__ void cast_f32_bf16_kernel(const float* __restrict__ in, bf16* __restrict__ out, int n) {
  int i = blockIdx.x * 256 + threadIdx.x;
  if (i < n) out[i] = (bf16)in[i];
}

// context -> bf16: txt rows 257..768 -> ctxt[512], img rows 0..256 -> ctxi[384] zero-padded
__global__ void prep_ctx_kernel(const float* __restrict__ ctx, bf16* __restrict__ ctxt,
                                bf16* __restrict__ ctxi) {
  int i = blockIdx.x * 256 + threadIdx.x;
  if (i < T5 * DIM) ctxt[i] = (bf16)ctx[(size_t)IMG * DIM + i];
  if (i < IMGP * DIM) {
    int r = i / DIM;
    ctxi[i] = (r < IMG) ? (bf16)ctx[i] : (bf16)0.0f;
  }
}

// transpose W (K x N, f32) -> Wt (N x K, bf16). K,N multiples of 32.
__global__ void transpose_w_kernel(const float* __restrict__ W, bf16* __restrict__ Wt,
                                   int K, int N) {
  __shared__ float tile[32][33];
  int n0 = blockIdx.x * 32, k0 = blockIdx.y * 32;
  int tx = threadIdx.x, ty = threadIdx.y;  // block (32,8)
  for (int i = ty; i < 32; i += 8)
    tile[i][tx] = W[(size_t)(k0 + i) * N + n0 + tx];
  __syncthreads();
  for (int i = ty; i < 32; i += 8)
    Wt[(size_t)(n0 + i) * K + k0 + tx] = (bf16)tile[tx][i];
}

// block=256, two-value sum reduction broadcast to all threads
__device__ inline void block_reduce2(float& s1, float& s2) {
  __shared__ float buf[8];
  for (int off = 32; off; off >>= 1) {
    s1 += __shfl_down(s1, off, 64);
    s2 += __shfl_down(s2, off, 64);
  }
  int w = threadIdx.x >> 6;
  if ((threadIdx.x & 63) == 0) { buf[w] = s1; buf[w + 4] = s2; }
  __syncthreads();
  s1 = buf[0] + buf[1] + buf[2] + buf[3];
  s2 = buf[4] + buf[5] + buf[6] + buf[7];
  __syncthreads();
}

// y = LN(x) * (gamma (+1?)) + beta ; one block per row
__global__ __launch_bounds__(256) void ln_mod_kernel(
    const float* __restrict__ X, const float* __restrict__ gamma,
    const float* __restrict__ beta, int plus_one, bf16* __restrict__ out) {
  int r = blockIdx.x;
  const float* xr = X + (size_t)r * DIM;
  float v[6], s = 0.f, s2 = 0.f;
  for (int i = 0; i < 6; i++) {
    v[i] = xr[threadIdx.x + i * 256];
    s += v[i]; s2 += v[i] * v[i];
  }
  block_reduce2(s, s2);
  float mean = s * (1.0f / DIM);
  float var = s2 * (1.0f / DIM) - mean * mean;
  float rstd = rsqrtf(var + EPSL);
  float add1 = plus_one ? 1.0f : 0.0f;
  for (int i = 0; i < 6; i++) {
    int c = threadIdx.x + i * 256;
    out[(size_t)r * DIM + c] = (bf16)(((v[i] - mean) * rstd) * (gamma[c] + add1) + beta[c]);
  }
}

// strided row-in, mode: 0 = plain cast, 1 = rms, 2 = rms+rope. f32 in -> bf16 out (row stride DIM).
__global__ __launch_bounds__(256) void rms_rope_kernel(
    const float* __restrict__ X, int istride, const float* __restrict__ nw,
    const float* __restrict__ freqs, int mode, bf16* __restrict__ out) {
  int r = blockIdx.x;
  const float* xr = X + (size_t)r * istride;
  float v[6];
  for (int i = 0; i < 6; i++) v[i] = xr[threadIdx.x + i * 256];
  if (mode == 0) {
    for (int i = 0; i < 6; i++)
      out[(size_t)r * DIM + threadIdx.x + i * 256] = (bf16)v[i];
    return;
  }
  float s2 = 0.f, dummy = 0.f;
  for (int i = 0; i < 6; i++) s2 += v[i] * v[i];
  block_reduce2(s2, dummy);
  float rms = rsqrtf(s2 * (1.0f / DIM) + EPSL);
  if (mode == 1) {
    for (int i = 0; i < 6; i++) {
      int c = threadIdx.x + i * 256;
      out[(size_t)r * DIM + c] = (bf16)(v[i] * rms * nw[c]);
    }
  } else {
    int f = r / (18 * 24), rem = r % (18 * 24), hh = rem / 24, ww = rem % 24;
    for (int i = 0; i < 3; i++) {
      int p = threadIdx.x + i * 256;  // pair index
      int id = p & 63;
      int idx = id < 22 ? f : (id < 43 ? hh : ww);
      float th = freqs[idx * 64 + id];
      float cs = __cosf(th), sn = __sinf(th);
      float re = xr[2 * p] * rms * nw[2 * p];
      float im = xr[2 * p + 1] * rms * nw[2 * p + 1];
      out[(size_t)r * DIM + 2 * p]     = (bf16)(re * cs - im * sn);
      out[(size_t)r * DIM + 2 * p + 1] = (bf16)(re * sn + im * cs);
    }
  }
}

// ---------------- GEMM: C[M,N] = A[M,K](bf16) @ Wt[N,K]^T + epilogue ----------------
// m97 structure: BK=32, un-padded LDS (64B row stride -> conflict-free b128 frag reads),
// global_load_lds width-16 staging. M multiple of BM, N multiple of 128, K multiple of 32.
// epilogue: t = acc + bias[col]; if gelu: gelu_tanh(t); t *= scalev[col]; t += resid; store.
template <int BM>
__global__ __launch_bounds__(256) void gemm_glds_kernel(
    const bf16* __restrict__ A, const bf16* __restrict__ Wt,
    const float* __restrict__ bias, const float* __restrict__ scalev,
    const float* __restrict__ resid, float* __restrict__ outF,
    bf16* __restrict__ outB, int M, int N, int K, int gelu) {
  constexpr int MI = BM / 32;       // 4 for BM=128, 2 for BM=64
  constexpr int NAW = BM / 64;      // glds calls per wave for A
  __shared__ bf16 As[BM * 32];
  __shared__ bf16 Bs[128 * 32];
  int tid = threadIdx.x;
  int tm0 = blockIdx.y * BM, tn0 = blockIdx.x * 128;
  int lane = tid & 63, wave = tid >> 6;
  int quad = lane >> 4, l16 = lane & 15;
  int mbase = (wave >> 1) * (BM / 2), nbase = (wave & 1) * 64;

  // staging addresses: chunk c = 1024B = 16 rows; lane l -> row c*16 + l/4, col (l&3)*8
  int lrow = lane >> 2, lcol = (lane & 3) * 8;
  const bf16* aP[NAW];
  bf16* aL[NAW];
  for (int j = 0; j < NAW; j++) {
    int c = wave * NAW + j;
    aP[j] = A + (size_t)(tm0 + c * 16 + lrow) * K + lcol;
    aL[j] = &As[c * 512];
  }
  const bf16* bP[2];
  bf16* bL[2];
  for (int j = 0; j < 2; j++) {
    int c = wave * 2 + j;
    bP[j] = Wt + (size_t)(tn0 + c * 16 + lrow) * K + lcol;
    bL[j] = &Bs[c * 512];
  }

  f32x4 acc[MI][4];
  for (int mi = 0; mi < MI; mi++)
    for (int ni = 0; ni < 4; ni++)
      for (int rr = 0; rr < 4; rr++) acc[mi][ni][rr] = 0.0f;

  for (int k0 = 0; k0 < K; k0 += 32) {
    __syncthreads();
    for (int j = 0; j < NAW; j++) glds16(aP[j], aL[j]);
    for (int j = 0; j < 2; j++) glds16(bP[j], bL[j]);
    for (int j = 0; j < NAW; j++) aP[j] += 32;
    for (int j = 0; j < 2; j++) bP[j] += 32;
    __syncthreads();
    bf16x8 af[MI], bfr[4];
    for (int mi = 0; mi < MI; mi++)
      af[mi] = *(bf16x8*)&As[(mbase + mi * 16 + l16) * 32 + quad * 8];
    for (int ni = 0; ni < 4; ni++)
      bfr[ni] = *(bf16x8*)&Bs[(nbase + ni * 16 + l16) * 32 + quad * 8];
    for (int mi = 0; mi < MI; mi++)
      for (int ni = 0; ni < 4; ni++)
        acc[mi][ni] = __builtin_amdgcn_mfma_f32_16x16x32_bf16(af[mi], bfr[ni], acc[mi][ni], 0, 0, 0);
  }

  for (int mi = 0; mi < MI; mi++) {
    int rbase = tm0 + mbase + mi * 16 + quad * 4;
    for (int ni = 0; ni < 4; ni++) {
      int col = tn0 + nbase + ni * 16 + l16;
      float b = bias ? bias[col] : 0.0f;
      float sc = scalev ? scalev[col] : 1.0f;
      for (int rr = 0; rr < 4; rr++) {
        int row = rbase + rr;
        float t = acc[mi][ni][rr] + b;
        if (gelu) {
          float z = t;
          float u = 0.7978845608028654f * (z + 0.044715f * z * z * z);
          t = z / (1.0f + __expf(-2.0f * u));  // == 0.5z(1+tanh(u)), saturates safely
        }
        t *= sc;
        size_t idx = (size_t)row * N + col;
        if (resid) t += resid[idx];
        if (outF) outF[idx] = t;
        else outB[idx] = (bf16)t;
      }
    }
  }
}

// ---------------- Flash attention (bf16 MFMA, online softmax) ----------------
__global__ __launch_bounds__(256) void attn_kernel(
    const bf16* __restrict__ Q, const bf16* __restrict__ Kb, const bf16* __restrict__ Vb,
    float* __restrict__ outF, bf16* __restrict__ outB, int L, int mode) {
  __shared__ bf16 Ks[32][136];
  __shared__ bf16 Vts[128][40];
  __shared__ bf16 Ps[4][16][40];
  int tid = threadIdx.x;
  int hb = blockIdx.y;
  int q0 = blockIdx.x * 64;
  int lane = tid & 63, wave = tid >> 6;
  int quad = lane >> 4, l16 = lane & 15;
  int qrow = q0 + wave * 16 + l16;

  bf16x8 qf[4];
  for (int c = 0; c < 4; c++)
    qf[c] = *(const bf16x8*)(Q + (size_t)qrow * DIM + hb * HD + c * 32 + quad * 8);

  f32x4 o[8];
  for (int ff = 0; ff < 8; ff++)
    for (int rr = 0; rr < 4; rr++) o[ff][rr] = 0.0f;
  float m_i[4], l_i[4];
  for (int r = 0; r < 4; r++) { m_i[r] = -1e30f; l_i[r] = 0.0f; }
  const float sc = 0.08838834764831845f;  // 1/sqrt(128)

  int srow = tid >> 3, scol = (tid & 7) * 16;
  int nt = (L + 31) / 32;
  for (int kt = 0; kt < nt; kt++) {
    __syncthreads();
    int key = kt * 32 + srow;
    bf16x8 k0v = zero_bf16x8(), k1v = zero_bf16x8();
    bf16x8 v0v = zero_bf16x8(), v1v = zero_bf16x8();
    if (key < L) {
      const bf16* kp = Kb + (size_t)key * DIM + hb * HD + scol;
      k0v = *(const bf16x8*)kp; k1v = *(const bf16x8*)(kp + 8);
      const bf16* vp = Vb + (size_t)key * DIM + hb * HD + scol;
      v0v = *(const bf16x8*)vp; v1v = *(const bf16x8*)(vp + 8);
    }
    *(bf16x8*)&Ks[srow][scol] = k0v;
    *(bf16x8*)&Ks[srow][scol + 8] = k1v;
    for (int j = 0; j < 8; j++) Vts[scol + j][srow] = v0v[j];
    for (int j = 0; j < 8; j++) Vts[scol + 8 + j][srow] = v1v[j];
    __syncthreads();

    f32x4 sfr[2];
    for (int nf = 0; nf < 2; nf++) {
      f32x4 a;
      for (int rr = 0; rr < 4; rr++) a[rr] = 0.0f;
      for (int c = 0; c < 4; c++) {
        bf16x8 kf = *(bf16x8*)&Ks[nf * 16 + l16][c * 32 + quad * 8];
        a = __builtin_amdgcn_mfma_f32_16x16x32_bf16(qf[c], kf, a, 0, 0, 0);
      }
      sfr[nf] = a;
    }
    for (int nf = 0; nf < 2; nf++) {
      int colg = kt * 32 + nf * 16 + l16;
      bool valid = colg < L;
      for (int r = 0; r < 4; r++)
        sfr[nf][r] = valid ? sfr[nf][r] * sc : -1e30f;
    }
    float mnew[4], alpha[4];
    for (int r = 0; r < 4; r++) {
      float t = fmaxf(sfr[0][r], sfr[1][r]);
      for (int off = 1; off < 16; off <<= 1) t = fmaxf(t, __shfl_xor(t, off, 64));
      mnew[r] = fmaxf(m_i[r], t);
      alpha[r] = __expf(m_i[r] - mnew[r]);
      m_i[r] = mnew[r];
    }
    for (int r = 0; r < 4; r++) {
      float p0 = __expf(sfr[0][r] - mnew[r]);
      float p1 = __expf(sfr[1][r] - mnew[r]);
      Ps[wave][quad * 4 + r][l16] = (bf16)p0;
      Ps[wave][quad * 4 + r][16 + l16] = (bf16)p1;
      float t = p0 + p1;
      for (int off = 1; off < 16; off <<= 1) t += __shfl_xor(t, off, 64);
      l_i[r] = l_i[r] * alpha[r] + t;
      for (int ff = 0; ff < 8; ff++) o[ff][r] *= alpha[r];
    }
    __syncthreads();
    bf16x8 pf = *(bf16x8*)&Ps[wave][l16][quad * 8];
    for (int ff = 0; ff < 8; ff++) {
      bf16x8 vf = *(bf16x8*)&Vts[ff * 16 + l16][quad * 8];
      o[ff] = __builtin_amdgcn_mfma_f32_16x16x32_bf16(pf, vf, o[ff], 0, 0, 0);
    }
  }

  for (int r = 0; r < 4; r++) {
    float inv = 1.0f / l_i[r];
    for (int ff = 0; ff < 8; ff++) o[ff][r] *= inv;
  }
  for (int ff = 0; ff < 8; ff++) {
    for (int r = 0; r < 4; r++) {
      int row = q0 + wave * 16 + quad * 4 + r;
      int col = hb * HD + ff * 16 + l16;
      size_t idx = (size_t)row * DIM + col;
      if (mode == 0) outB[idx] = (bf16)o[ff][r];
      else if (mode == 1) outF[idx] = o[ff][r];
      else outF[idx] += o[ff][r];
    }
  }
}

// ---------------- host orchestration ----------------

extern "C" void kernel_launch(void* const* d_in, const int* in_sizes, int n_in,
                              void* d_out, int out_size, void* d_ws, size_t ws_size,
                              hipStream_t stream) {
  const float* x      = (const float*)d_in[0];
  const float* e      = (const float*)d_in[1];
  const float* ctx    = (const float*)d_in[2];
  const float* freqs  = (const float*)d_in[3];
  const float* modv   = (const float*)d_in[4];
  const float* sa_qw  = (const float*)d_in[5];
  const float* sa_qb  = (const float*)d_in[6];
  const float* sa_kw  = (const float*)d_in[7];
  const float* sa_kb  = (const float*)d_in[8];
  const float* sa_vw  = (const float*)d_in[9];
  const float* sa_vb  = (const float*)d_in[10];
  const float* sa_ow  = (const float*)d_in[11];
  const float* sa_ob  = (const float*)d_in[12];
  const float* sa_nq  = (const float*)d_in[13];
  const float* sa_nk  = (const float*)d_in[14];
  const float* norm3w = (const float*)d_in[15];
  const float* norm3b = (const float*)d_in[16];
  const float* ca_qw  = (const float*)d_in[17];
  const float* ca_qb  = (const float*)d_in[18];
  const float* ca_kw  = (const float*)d_in[19];
  const float* ca_kb  = (const float*)d_in[20];
  const float* ca_vw  = (const float*)d_in[21];
  const float* ca_vb  = (const float*)d_in[22];
  const float* ca_kiw = (const float*)d_in[23];
  const float* ca_kib = (const float*)d_in[24];
  const float* ca_viw = (const float*)d_in[25];
  const float* ca_vib = (const float*)d_in[26];
  const float* ca_ow  = (const float*)d_in[27];
  const float* ca_ob  = (const float*)d_in[28];
  const float* ca_nq  = (const float*)d_in[29];
  const float* ca_nk  = (const float*)d_in[30];
  const float* ca_nki = (const float*)d_in[31];
  const float* ffn_w1 = (const float*)d_in[32];
  const float* ffn_b1 = (const float*)d_in[33];
  const float* ffn_w2 = (const float*)d_in[34];
  const float* ffn_b2 = (const float*)d_in[35];

  char* ws = (char*)d_ws;
  size_t off = 0;
  auto alloc = [&](size_t bytes) -> void* {
    void* p = ws + off;
    off += (bytes + 255) & ~(size_t)255;
    return p;
  };
  float* e6f   = (float*)alloc((size_t)6 * DIM * 4);
  bf16* act_bf = (bf16*)alloc((size_t)SQ * DIM * 2);
  bf16* q_bf   = (bf16*)alloc((size_t)SQ * DIM * 2);
  bf16* k_bf   = (bf16*)alloc((size_t)SQ * DIM * 2);
  bf16* v_bf   = (bf16*)alloc((size_t)SQ * DIM * 2);
  // big0 shared region: qkvF [SQ,4608] f32  ->  projf [SQ,DIM] f32  ->  y1 [SQ,FFN] bf16
  char* big0   = (char*)alloc((size_t)SQ * 3 * DIM * 4);
  float* xcur  = (float*)alloc((size_t)SQ * DIM * 4);
  bf16* wbig   = (bf16*)alloc((size_t)FFN * DIM * 2);   // qkvT / w1T / w2T (sequential reuse)
  bf16* wsm    = (bf16*)alloc((size_t)3 * DIM * DIM * 2); // owT/qT/kvT (sequential reuse)
  bf16* ctxt_bf = (bf16*)alloc((size_t)T5 * DIM * 2);
  bf16* ctxi_bf = (bf16*)alloc((size_t)IMGP * DIM * 2);
  float* ctxkvF = (float*)alloc((size_t)T5 * 2 * DIM * 4);
  float* ctxkivF = (float*)alloc((size_t)IMGP * 2 * DIM * 4);
  bf16* kt_bf  = (bf16*)alloc((size_t)T5 * DIM * 2);
  bf16* vt_bf  = (bf16*)alloc((size_t)T5 * DIM * 2);
  bf16* ki_bf  = (bf16*)alloc((size_t)IMGP * DIM * 2);
  bf16* vi_bf  = (bf16*)alloc((size_t)IMGP * DIM * 2);
  float* qkvB  = (float*)alloc((size_t)3 * DIM * 4);
  float* kvB   = (float*)alloc((size_t)2 * DIM * 4);
  float* kivB  = (float*)alloc((size_t)2 * DIM * 4);

  float* qkvF = (float*)big0;
  float* projf = (float*)big0;
  bf16* y1 = (bf16*)big0;

  const float* e0 = e6f;
  const float* e1 = e6f + DIM;
  const float* e2 = e6f + 2 * DIM;
  const float* e3 = e6f + 3 * DIM;
  const float* e4 = e6f + 4 * DIM;
  const float* e5 = e6f + 5 * DIM;

  dim3 tblk(32, 8);
  dim3 tg_sq(DIM / 32, DIM / 32);
  dim3 ag(SQ / 64, NHEADS);

  // e6 = modulation + e ; bias concats
  add_vec_kernel<<<(6 * DIM + 255) / 256, 256, 0, stream>>>(modv, e, e6f, 6 * DIM);
  hipMemcpyAsync(qkvB, sa_qb, DIM * 4, hipMemcpyDeviceToDevice, stream);
  hipMemcpyAsync(qkvB + DIM, sa_kb, DIM * 4, hipMemcpyDeviceToDevice, stream);
  hipMemcpyAsync(qkvB + 2 * DIM, sa_vb, DIM * 4, hipMemcpyDeviceToDevice, stream);
  hipMemcpyAsync(kvB, ca_kb, DIM * 4, hipMemcpyDeviceToDevice, stream);
  hipMemcpyAsync(kvB + DIM, ca_vb, DIM * 4, hipMemcpyDeviceToDevice, stream);
  hipMemcpyAsync(kivB, ca_kib, DIM * 4, hipMemcpyDeviceToDevice, stream);
  hipMemcpyAsync(kivB + DIM, ca_vib, DIM * 4, hipMemcpyDeviceToDevice, stream);

  // xs = LN(x)*(1+e1)+e0
  ln_mod_kernel<<<SQ, 256, 0, stream>>>(x, e1, e0, 1, act_bf);

  // ---- self attention: batched QKV ----
  transpose_w_kernel<<<tg_sq, tblk, 0, stream>>>(sa_qw, wbig, DIM, DIM);
  transpose_w_kernel<<<tg_sq, tblk, 0, stream>>>(sa_kw, wbig + (size_t)DIM * DIM, DIM, DIM);
  transpose_w_kernel<<<tg_sq, tblk, 0, stream>>>(sa_vw, wbig + (size_t)2 * DIM * DIM, DIM, DIM);
  gemm_glds_kernel<128><<<dim3(3 * DIM / 128, SQ / 128), 256, 0, stream>>>(
      act_bf, wbig, qkvB, nullptr, nullptr, qkvF, nullptr, SQ, 3 * DIM, DIM, 0);
  rms_rope_kernel<<<SQ, 256, 0, stream>>>(qkvF, 3 * DIM, sa_nq, freqs, 2, q_bf);
  rms_rope_kernel<<<SQ, 256, 0, stream>>>(qkvF + DIM, 3 * DIM, sa_nk, freqs, 2, k_bf);
  rms_rope_kernel<<<SQ, 256, 0, stream>>>(qkvF + 2 * DIM, 3 * DIM, nullptr, freqs, 0, v_bf);

  attn_kernel<<<ag, 256, 0, stream>>>(q_bf, k_bf, v_bf, nullptr, act_bf, SQ, 0);

  // x = x + (attn @ sa_ow + sa_ob) * e2
  transpose_w_kernel<<<tg_sq, tblk, 0, stream>>>(sa_ow, wsm, DIM, DIM);
  gemm_glds_kernel<64><<<dim3(DIM / 128, SQ / 64), 256, 0, stream>>>(
      act_bf, wsm, sa_ob, e2, x, xcur, nullptr, SQ, DIM, DIM, 0);

  // ---- cross attention ----
  ln_mod_kernel<<<SQ, 256, 0, stream>>>(xcur, norm3w, norm3b, 0, act_bf);

  transpose_w_kernel<<<tg_sq, tblk, 0, stream>>>(ca_qw, wsm, DIM, DIM);
  gemm_glds_kernel<64><<<dim3(DIM / 128, SQ / 64), 256, 0, stream>>>(
      act_bf, wsm, ca_qb, nullptr, nullptr, projf, nullptr, SQ, DIM, DIM, 0);
  rms_rope_kernel<<<SQ, 256, 0, stream>>>(projf, DIM, ca_nq, freqs, 1, q_bf);

  prep_ctx_kernel<<<(T5 * DIM + 255) / 256, 256, 0, stream>>>(ctx, ctxt_bf, ctxi_bf);

  // txt K||V batched (M=512, N=3072)
  transpose_w_kernel<<<tg_sq, tblk, 0, stream>>>(ca_kw, wsm, DIM, DIM);
  transpose_w_kernel<<<tg_sq, tblk, 0, stream>>>(ca_vw, wsm + (size_t)DIM * DIM, DIM, DIM);
  gemm_glds_kernel<64><<<dim3(2 * DIM / 128, T5 / 64), 256, 0, stream>>>(
      ctxt_bf, wsm, kvB, nullptr, nullptr, ctxkvF, nullptr, T5, 2 * DIM, DIM, 0);
  rms_rope_kernel<<<T5, 256, 0, stream>>>(ctxkvF, 2 * DIM, ca_nk, freqs, 1, kt_bf);
  rms_rope_kernel<<<T5, 256, 0, stream>>>(ctxkvF + DIM, 2 * DIM, nullptr, freqs, 0, vt_bf);

  // img KI||VI batched (M=384 padded, N=3072)
  transpose_w_kernel<<<tg_sq, tblk, 0, stream>>>(ca_kiw, wsm, DIM, DIM);
  transpose_w_kernel<<<tg_sq, tblk, 0, stream>>>(ca_viw, wsm + (size_t)DIM * DIM, DIM, DIM);
  gemm_glds_kernel<64><<<dim3(2 * DIM / 128, IMGP / 64), 256, 0, stream>>>(
      ctxi_bf, wsm, kivB, nullptr, nullptr, ctxkivF, nullptr, IMGP, 2 * DIM, DIM, 0);
  rms_rope_kernel<<<IMGP, 256, 0, stream>>>(ctxkivF, 2 * DIM, ca_nki, freqs, 1, ki_bf);
  rms_rope_kernel<<<IMGP, 256, 0, stream>>>(ctxkivF + DIM, 2 * DIM, nullptr, freqs, 0, vi_bf);

  attn_kernel<<<ag, 256, 0, stream>>>(q_bf, kt_bf, vt_bf, projf, nullptr, T5, 1);
  attn_kernel<<<ag, 256, 0, stream>>>(q_bf, ki_bf, vi_bf, projf, nullptr, IMG, 2);
  cast_f32_bf16_kernel<<<(SQ * DIM + 255) / 256, 256, 0, stream>>>(projf, act_bf, SQ * DIM);

  // x = x + attn2 @ ca_ow + ca_ob
  transpose_w_kernel<<<tg_sq, tblk, 0, stream>>>(ca_ow, wsm, DIM, DIM);
  gemm_glds_kernel<64><<<dim3(DIM / 128, SQ / 64), 256, 0, stream>>>(
      act_bf, wsm, ca_ob, nullptr, xcur, xcur, nullptr, SQ, DIM, DIM, 0);

  // ---- FFN ----
  ln_mod_kernel<<<SQ, 256, 0, stream>>>(xcur, e4, e3, 1, act_bf);

  transpose_w_kernel<<<dim3(FFN / 32, DIM / 32), tblk, 0, stream>>>(ffn_w1, wbig, DIM, FFN);
  gemm_glds_kernel<128><<<dim3(FFN / 128, SQ / 128), 256, 0, stream>>>(
      act_bf, wbig, ffn_b1, nullptr, nullptr, nullptr, y1, SQ, FFN, DIM, 1);

  transpose_w_kernel<<<dim3(DIM / 32, FFN / 32), tblk, 0, stream>>>(ffn_w2, wbig, FFN, DIM);
  gemm_glds_kernel<64><<<dim3(DIM / 128, SQ / 64), 256, 0, stream>>>(
      y1, wbig, ffn_b2, e5, xcur, (float*)d_out, nullptr, SQ, DIM, FFN, 0);
}

// Round 4
// 1476.656 us; speedup vs baseline: 3.6288x; 2.0048x over previous
//
#include <hip/hip_runtime.h>

#define DIM 1536
#define NHEADS 12
#define HD 128
#define FFN 8960
#define SQ 3456
#define T5 512
#define LCTX 769
#define IMG 257
#define IMGP 384
#define EPSL 1e-6f

typedef __bf16 bf16;
typedef __bf16 bf16x8 __attribute__((ext_vector_type(8)));
typedef float f32x4 __attribute__((ext_vector_type(4)));

__device__ inline bf16x8 zero_bf16x8() {
  bf16x8 v;
  for (int i = 0; i < 8; i++) v[i] = (bf16)0.0f;
  return v;
}

// async 16B global -> LDS. lds base must be wave-uniform; lane i lands at lds + i*16.
__device__ inline void glds16(const bf16* g, bf16* lds) {
  __builtin_amdgcn_global_load_lds(
      (const __attribute__((address_space(1))) void*)g,
      (__attribute__((address_space(3))) void*)lds, 16, 0, 0);
}

// ---------------- small utility kernels ----------------

// e6 = modulation + e ; bias concats (replaces 7 hipMemcpyAsync)
__global__ void prep_small_kernel(const float* __restrict__ modv, const float* __restrict__ e,
                                  float* __restrict__ e6f,
                                  const float* __restrict__ qb, const float* __restrict__ kb,
                                  const float* __restrict__ vb, float* __restrict__ qkvB,
                                  const float* __restrict__ ckb, const float* __restrict__ cvb,
                                  float* __restrict__ kvB,
                                  const float* __restrict__ kib, const float* __restrict__ vib,
                                  float* __restrict__ kivB) {
  int i = blockIdx.x * 256 + threadIdx.x;
  if (i < 6 * DIM) e6f[i] = modv[i] + e[i];
  if (i < DIM) {
    qkvB[i] = qb[i]; qkvB[i + DIM] = kb[i]; qkvB[i + 2 * DIM] = vb[i];
    kvB[i] = ckb[i]; kvB[i + DIM] = cvb[i];
    kivB[i] = kib[i]; kivB[i + DIM] = vib[i];
  }
}

__global__ void cast_f32_bf16_kernel(const float* __restrict__ in, bf16* __restrict__ out, int n) {
  int i = blockIdx.x * 256 + threadIdx.x;
  if (i < n) out[i] = (bf16)in[i];
}

// context -> bf16: txt rows 257..768 -> ctxt[512], img rows 0..256 -> ctxi[384] zero-padded
__global__ void prep_ctx_kernel(const float* __restrict__ ctx, bf16* __restrict__ ctxt,
                                bf16* __restrict__ ctxi) {
  int i = blockIdx.x * 256 + threadIdx.x;
  if (i < T5 * DIM) ctxt[i] = (bf16)ctx[(size_t)IMG * DIM + i];
  if (i < IMGP * DIM) {
    int r = i / DIM;
    ctxi[i] = (r < IMG) ? (bf16)ctx[i] : (bf16)0.0f;
  }
}

// transpose up to 3 weights W (K x N, f32) -> Wt (N x K, bf16), z selects source/dest slot.
__global__ void transpose_w3_kernel(const float* __restrict__ W0, const float* __restrict__ W1,
                                    const float* __restrict__ W2, bf16* __restrict__ Wt,
                                    int K, int N) {
  __shared__ float tile[32][33];
  const float* W = blockIdx.z == 0 ? W0 : (blockIdx.z == 1 ? W1 : W2);
  bf16* dst = Wt + (size_t)blockIdx.z * K * N;
  int n0 = blockIdx.x * 32, k0 = blockIdx.y * 32;
  int tx = threadIdx.x, ty = threadIdx.y;  // block (32,8)
  for (int i = ty; i < 32; i += 8)
    tile[i][tx] = W[(size_t)(k0 + i) * N + n0 + tx];
  __syncthreads();
  for (int i = ty; i < 32; i += 8)
    dst[(size_t)(n0 + i) * K + k0 + tx] = (bf16)tile[tx][i];
}

// block=256, two-value sum reduction broadcast to all threads
__device__ inline void block_reduce2(float& s1, float& s2) {
  __shared__ float buf[8];
  for (int off = 32; off; off >>= 1) {
    s1 += __shfl_down(s1, off, 64);
    s2 += __shfl_down(s2, off, 64);
  }
  int w = threadIdx.x >> 6;
  if ((threadIdx.x & 63) == 0) { buf[w] = s1; buf[w + 4] = s2; }
  __syncthreads();
  s1 = buf[0] + buf[1] + buf[2] + buf[3];
  s2 = buf[4] + buf[5] + buf[6] + buf[7];
  __syncthreads();
}

// y = LN(x) * (gamma (+1?)) + beta ; one block per row
__global__ __launch_bounds__(256) void ln_mod_kernel(
    const float* __restrict__ X, const float* __restrict__ gamma,
    const float* __restrict__ beta, int plus_one, bf16* __restrict__ out) {
  int r = blockIdx.x;
  const float* xr = X + (size_t)r * DIM;
  float v[6], s = 0.f, s2 = 0.f;
  for (int i = 0; i < 6; i++) {
    v[i] = xr[threadIdx.x + i * 256];
    s += v[i]; s2 += v[i] * v[i];
  }
  block_reduce2(s, s2);
  float mean = s * (1.0f / DIM);
  float var = s2 * (1.0f / DIM) - mean * mean;
  float rstd = rsqrtf(var + EPSL);
  float add1 = plus_one ? 1.0f : 0.0f;
  for (int i = 0; i < 6; i++) {
    int c = threadIdx.x + i * 256;
    out[(size_t)r * DIM + c] = (bf16)(((v[i] - mean) * rstd) * (gamma[c] + add1) + beta[c]);
  }
}

// fused per-row postprocess of a GEMM f32 output with row stride `istride`:
// blockIdx.y = section; per section: mode 0=cast, 1=rms, 2=rms+rope
__global__ __launch_bounds__(256) void rms_rope_multi_kernel(
    const float* __restrict__ X, int istride, int nsec,
    const float* __restrict__ nw0, const float* __restrict__ nw1,
    int mode0, int mode1, int mode2,
    const float* __restrict__ freqs,
    bf16* __restrict__ o0, bf16* __restrict__ o1, bf16* __restrict__ o2) {
  int sec = blockIdx.y;
  int r = blockIdx.x;
  const float* xr = X + (size_t)r * istride + sec * DIM;
  const float* nw = sec == 0 ? nw0 : nw1;
  bf16* out = (sec == 0 ? o0 : (sec == 1 ? o1 : o2)) + (size_t)r * DIM;
  int mode = sec == 0 ? mode0 : (sec == 1 ? mode1 : mode2);
  float v[6];
  for (int i = 0; i < 6; i++) v[i] = xr[threadIdx.x + i * 256];
  if (mode == 0) {
    for (int i = 0; i < 6; i++) out[threadIdx.x + i * 256] = (bf16)v[i];
    return;
  }
  float s2 = 0.f, dummy = 0.f;
  for (int i = 0; i < 6; i++) s2 += v[i] * v[i];
  block_reduce2(s2, dummy);
  float rms = rsqrtf(s2 * (1.0f / DIM) + EPSL);
  if (mode == 1) {
    for (int i = 0; i < 6; i++) {
      int c = threadIdx.x + i * 256;
      out[c] = (bf16)(v[i] * rms * nw[c]);
    }
  } else {
    int f = r / (18 * 24), rem = r % (18 * 24), hh = rem / 24, ww = rem % 24;
    for (int i = 0; i < 3; i++) {
      int p = threadIdx.x + i * 256;  // pair index
      int id = p & 63;
      int idx = id < 22 ? f : (id < 43 ? hh : ww);
      float th = freqs[idx * 64 + id];
      float cs = __cosf(th), sn = __sinf(th);
      float re = xr[2 * p] * rms * nw[2 * p];
      float im = xr[2 * p + 1] * rms * nw[2 * p + 1];
      out[2 * p]     = (bf16)(re * cs - im * sn);
      out[2 * p + 1] = (bf16)(re * sn + im * cs);
    }
  }
}

// FFN2 split-K reduce: out = xcur + (p0 + p1 + b2[col]) * e5[col]
__global__ void ffn2_reduce_kernel(const float* __restrict__ p, const float* __restrict__ b2,
                                   const float* __restrict__ e5, const float* __restrict__ xcur,
                                   float* __restrict__ out) {
  int i = blockIdx.x * 256 + threadIdx.x;
  if (i >= SQ * DIM) return;
  int col = i % DIM;
  out[i] = xcur[i] + (p[i] + p[i + (size_t)SQ * DIM] + b2[col]) * e5[col];
}

// ---------------- GEMM: C[M,N] = A[M,K](bf16) @ Wt[N,K]^T + epilogue ----------------
// Double-buffered glds staging: prefetch tile k+1 before computing tile k so the
// barrier's vmcnt(0) drain overlaps the compute phase. BK=32, unpadded LDS rows (64B).
// ksplit>1: raw partials to outF + bz*M*N, no epilogue.
template <int BM>
__global__ __launch_bounds__(256) void gemm_db_kernel(
    const bf16* __restrict__ A, const bf16* __restrict__ Wt,
    const float* __restrict__ bias, const float* __restrict__ scalev,
    const float* __restrict__ resid, float* __restrict__ outF,
    bf16* __restrict__ outB, int M, int N, int K, int gelu, int ksplit) {
  constexpr int MI = BM / 32;
  constexpr int NAW = BM / 64;  // A glds per wave
  __shared__ bf16 As[2][BM * 32];
  __shared__ bf16 Bs[2][128 * 32];
  int tid = threadIdx.x;
  int tm0 = blockIdx.y * BM, tn0 = blockIdx.x * 128;
  int lane = tid & 63, wave = tid >> 6;
  int quad = lane >> 4, l16 = lane & 15;
  int mbase = (wave >> 1) * (BM / 2), nbase = (wave & 1) * 64;
  int lrow = lane >> 2, lcol = (lane & 3) * 8;
  int klen = K / ksplit;
  int kbeg = blockIdx.z * klen;

  const bf16* aP[NAW];
  const bf16* bP[2];
#pragma unroll
  for (int j = 0; j < NAW; j++) {
    int c = wave * NAW + j;
    aP[j] = A + (size_t)(tm0 + c * 16 + lrow) * K + kbeg + lcol;
  }
#pragma unroll
  for (int j = 0; j < 2; j++) {
    int c = wave * 2 + j;
    bP[j] = Wt + (size_t)(tn0 + c * 16 + lrow) * K + kbeg + lcol;
  }

  f32x4 acc[MI][4];
#pragma unroll
  for (int mi = 0; mi < MI; mi++)
    for (int ni = 0; ni < 4; ni++)
      for (int rr = 0; rr < 4; rr++) acc[mi][ni][rr] = 0.0f;

  // stage tile into buffer buf, advance pointers
  auto stage = [&](int buf) {
#pragma unroll
    for (int j = 0; j < NAW; j++) {
      glds16(aP[j], &As[buf][(wave * NAW + j) * 512]);
      aP[j] += 32;
    }
#pragma unroll
    for (int j = 0; j < 2; j++) {
      glds16(bP[j], &Bs[buf][(wave * 2 + j) * 512]);
      bP[j] += 32;
    }
  };

  int niter = klen / 32;
  stage(0);
  int cur = 0;
  for (int it = 0; it < niter; it++) {
    __syncthreads();               // drains vmcnt: tile `cur` resident in LDS
    if (it + 1 < niter) stage(cur ^ 1);  // prefetch overlaps compute below
    bf16x8 af[MI], bfr[4];
#pragma unroll
    for (int mi = 0; mi < MI; mi++)
      af[mi] = *(bf16x8*)&As[cur][(mbase + mi * 16 + l16) * 32 + quad * 8];
#pragma unroll
    for (int ni = 0; ni < 4; ni++)
      bfr[ni] = *(bf16x8*)&Bs[cur][(nbase + ni * 16 + l16) * 32 + quad * 8];
#pragma unroll
    for (int mi = 0; mi < MI; mi++)
#pragma unroll
      for (int ni = 0; ni < 4; ni++)
        acc[mi][ni] = __builtin_amdgcn_mfma_f32_16x16x32_bf16(af[mi], bfr[ni], acc[mi][ni], 0, 0, 0);
    cur ^= 1;
  }

  if (ksplit > 1) {
    float* po = outF + (size_t)blockIdx.z * M * N;
#pragma unroll
    for (int mi = 0; mi < MI; mi++) {
      int rbase = tm0 + mbase + mi * 16 + quad * 4;
#pragma unroll
      for (int ni = 0; ni < 4; ni++) {
        int col = tn0 + nbase + ni * 16 + l16;
        for (int rr = 0; rr < 4; rr++)
          po[(size_t)(rbase + rr) * N + col] = acc[mi][ni][rr];
      }
    }
    return;
  }

#pragma unroll
  for (int mi = 0; mi < MI; mi++) {
    int rbase = tm0 + mbase + mi * 16 + quad * 4;
#pragma unroll
    for (int ni = 0; ni < 4; ni++) {
      int col = tn0 + nbase + ni * 16 + l16;
      float b = bias ? bias[col] : 0.0f;
      float sc = scalev ? scalev[col] : 1.0f;
      for (int rr = 0; rr < 4; rr++) {
        int row = rbase + rr;
        float t = acc[mi][ni][rr] + b;
        if (gelu) {
          float z = t;
          float u = 0.7978845608028654f * (z + 0.044715f * z * z * z);
          t = z / (1.0f + __expf(-2.0f * u));  // == 0.5z(1+tanh(u))
        }
        t *= sc;
        size_t idx = (size_t)row * N + col;
        if (resid) t += resid[idx];
        if (outF) outF[idx] = t;
        else outB[idx] = (bf16)t;
      }
    }
  }
}

// ---------------- Flash attention (bf16 MFMA, online softmax) ----------------
__global__ __launch_bounds__(256) void attn_kernel(
    const bf16* __restrict__ Q, const bf16* __restrict__ Kb, const bf16* __restrict__ Vb,
    float* __restrict__ outF, bf16* __restrict__ outB, int L, int mode) {
  __shared__ bf16 Ks[32][136];
  __shared__ bf16 Vts[128][40];
  __shared__ bf16 Ps[4][16][40];
  int tid = threadIdx.x;
  int hb = blockIdx.y;
  int q0 = blockIdx.x * 64;
  int lane = tid & 63, wave = tid >> 6;
  int quad = lane >> 4, l16 = lane & 15;
  int qrow = q0 + wave * 16 + l16;

  bf16x8 qf[4];
  for (int c = 0; c < 4; c++)
    qf[c] = *(const bf16x8*)(Q + (size_t)qrow * DIM + hb * HD + c * 32 + quad * 8);

  f32x4 o[8];
  for (int ff = 0; ff < 8; ff++)
    for (int rr = 0; rr < 4; rr++) o[ff][rr] = 0.0f;
  float m_i[4], l_i[4];
  for (int r = 0; r < 4; r++) { m_i[r] = -1e30f; l_i[r] = 0.0f; }
  const float sc = 0.08838834764831845f;  // 1/sqrt(128)

  int srow = tid >> 3, scol = (tid & 7) * 16;
  int nt = (L + 31) / 32;
  for (int kt = 0; kt < nt; kt++) {
    __syncthreads();
    int key = kt * 32 + srow;
    bf16x8 k0v = zero_bf16x8(), k1v = zero_bf16x8();
    bf16x8 v0v = zero_bf16x8(), v1v = zero_bf16x8();
    if (key < L) {
      const bf16* kp = Kb + (size_t)key * DIM + hb * HD + scol;
      k0v = *(const bf16x8*)kp; k1v = *(const bf16x8*)(kp + 8);
      const bf16* vp = Vb + (size_t)key * DIM + hb * HD + scol;
      v0v = *(const bf16x8*)vp; v1v = *(const bf16x8*)(vp + 8);
    }
    *(bf16x8*)&Ks[srow][scol] = k0v;
    *(bf16x8*)&Ks[srow][scol + 8] = k1v;
    for (int j = 0; j < 8; j++) Vts[scol + j][srow] = v0v[j];
    for (int j = 0; j < 8; j++) Vts[scol + 8 + j][srow] = v1v[j];
    __syncthreads();

    f32x4 sfr[2];
    for (int nf = 0; nf < 2; nf++) {
      f32x4 a;
      for (int rr = 0; rr < 4; rr++) a[rr] = 0.0f;
      for (int c = 0; c < 4; c++) {
        bf16x8 kf = *(bf16x8*)&Ks[nf * 16 + l16][c * 32 + quad * 8];
        a = __builtin_amdgcn_mfma_f32_16x16x32_bf16(qf[c], kf, a, 0, 0, 0);
      }
      sfr[nf] = a;
    }
    for (int nf = 0; nf < 2; nf++) {
      int colg = kt * 32 + nf * 16 + l16;
      bool valid = colg < L;
      for (int r = 0; r < 4; r++)
        sfr[nf][r] = valid ? sfr[nf][r] * sc : -1e30f;
    }
    float mnew[4], alpha[4];
    for (int r = 0; r < 4; r++) {
      float t = fmaxf(sfr[0][r], sfr[1][r]);
      for (int off = 1; off < 16; off <<= 1) t = fmaxf(t, __shfl_xor(t, off, 64));
      mnew[r] = fmaxf(m_i[r], t);
      alpha[r] = __expf(m_i[r] - mnew[r]);
      m_i[r] = mnew[r];
    }
    for (int r = 0; r < 4; r++) {
      float p0 = __expf(sfr[0][r] - mnew[r]);
      float p1 = __expf(sfr[1][r] - mnew[r]);
      Ps[wave][quad * 4 + r][l16] = (bf16)p0;
      Ps[wave][quad * 4 + r][16 + l16] = (bf16)p1;
      float t = p0 + p1;
      for (int off = 1; off < 16; off <<= 1) t += __shfl_xor(t, off, 64);
      l_i[r] = l_i[r] * alpha[r] + t;
      for (int ff = 0; ff < 8; ff++) o[ff][r] *= alpha[r];
    }
    __syncthreads();
    bf16x8 pf = *(bf16x8*)&Ps[wave][l16][quad * 8];
    for (int ff = 0; ff < 8; ff++) {
      bf16x8 vf = *(bf16x8*)&Vts[ff * 16 + l16][quad * 8];
      o[ff] = __builtin_amdgcn_mfma_f32_16x16x32_bf16(pf, vf, o[ff], 0, 0, 0);
    }
  }

  for (int r = 0; r < 4; r++) {
    float inv = 1.0f / l_i[r];
    for (int ff = 0; ff < 8; ff++) o[ff][r] *= inv;
  }
  for (int ff = 0; ff < 8; ff++) {
    for (int r = 0; r < 4; r++) {
      int row = q0 + wave * 16 + quad * 4 + r;
      int col = hb * HD + ff * 16 + l16;
      size_t idx = (size_t)row * DIM + col;
      if (mode == 0) outB[idx] = (bf16)o[ff][r];
      else if (mode == 1) outF[idx] = o[ff][r];
      else outF[idx] += o[ff][r];
    }
  }
}

// ---------------- host orchestration ----------------

extern "C" void kernel_launch(void* const* d_in, const int* in_sizes, int n_in,
                              void* d_out, int out_size, void* d_ws, size_t ws_size,
                              hipStream_t stream) {
  const float* x      = (const float*)d_in[0];
  const float* e      = (const float*)d_in[1];
  const float* ctx    = (const float*)d_in[2];
  const float* freqs  = (const float*)d_in[3];
  const float* modv   = (const float*)d_in[4];
  const float* sa_qw  = (const float*)d_in[5];
  const float* sa_qb  = (const float*)d_in[6];
  const float* sa_kw  = (const float*)d_in[7];
  const float* sa_kb  = (const float*)d_in[8];
  const float* sa_vw  = (const float*)d_in[9];
  const float* sa_vb  = (const float*)d_in[10];
  const float* sa_ow  = (const float*)d_in[11];
  const float* sa_ob  = (const float*)d_in[12];
  const float* sa_nq  = (const float*)d_in[13];
  const float* sa_nk  = (const float*)d_in[14];
  const float* norm3w = (const float*)d_in[15];
  const float* norm3b = (const float*)d_in[16];
  const float* ca_qw  = (const float*)d_in[17];
  const float* ca_qb  = (const float*)d_in[18];
  const float* ca_kw  = (const float*)d_in[19];
  const float* ca_kb  = (const float*)d_in[20];
  const float* ca_vw  = (const float*)d_in[21];
  const float* ca_vb  = (const float*)d_in[22];
  const float* ca_kiw = (const float*)d_in[23];
  const float* ca_kib = (const float*)d_in[24];
  const float* ca_viw = (const float*)d_in[25];
  const float* ca_vib = (const float*)d_in[26];
  const float* ca_ow  = (const float*)d_in[27];
  const float* ca_ob  = (const float*)d_in[28];
  const float* ca_nq  = (const float*)d_in[29];
  const float* ca_nk  = (const float*)d_in[30];
  const float* ca_nki = (const float*)d_in[31];
  const float* ffn_w1 = (const float*)d_in[32];
  const float* ffn_b1 = (const float*)d_in[33];
  const float* ffn_w2 = (const float*)d_in[34];
  const float* ffn_b2 = (const float*)d_in[35];

  char* ws = (char*)d_ws;
  size_t off = 0;
  auto alloc = [&](size_t bytes) -> void* {
    void* p = ws + off;
    off += (bytes + 255) & ~(size_t)255;
    return p;
  };
  // act/q/k/v region is dead by FFN2 time; reused as split-K partial buffer (42.5 MB)
  float* e6f   = (float*)alloc((size_t)6 * DIM * 4);
  bf16* act_bf = (bf16*)alloc((size_t)SQ * DIM * 2);
  bf16* q_bf   = (bf16*)alloc((size_t)SQ * DIM * 2);
  bf16* k_bf   = (bf16*)alloc((size_t)SQ * DIM * 2);
  bf16* v_bf   = (bf16*)alloc((size_t)SQ * DIM * 2);
  // big0 shared region: qkvF [SQ,4608] f32  ->  projf [SQ,DIM] f32  ->  y1 [SQ,FFN] bf16
  char* big0   = (char*)alloc((size_t)SQ * 3 * DIM * 4);
  float* xcur  = (float*)alloc((size_t)SQ * DIM * 4);
  bf16* wbig   = (bf16*)alloc((size_t)FFN * DIM * 2);     // qkvT / w1T / w2T (sequential reuse)
  bf16* wsm    = (bf16*)alloc((size_t)3 * DIM * DIM * 2); // owT/qT/kvT (sequential reuse)
  bf16* ctxt_bf = (bf16*)alloc((size_t)T5 * DIM * 2);
  bf16* ctxi_bf = (bf16*)alloc((size_t)IMGP * DIM * 2);
  float* ctxkvF = (float*)alloc((size_t)T5 * 2 * DIM * 4);
  float* ctxkivF = (float*)alloc((size_t)IMGP * 2 * DIM * 4);
  bf16* kt_bf  = (bf16*)alloc((size_t)T5 * DIM * 2);
  bf16* vt_bf  = (bf16*)alloc((size_t)T5 * DIM * 2);
  bf16* ki_bf  = (bf16*)alloc((size_t)IMGP * DIM * 2);
  bf16* vi_bf  = (bf16*)alloc((size_t)IMGP * DIM * 2);
  float* qkvB  = (float*)alloc((size_t)3 * DIM * 4);
  float* kvB   = (float*)alloc((size_t)2 * DIM * 4);
  float* kivB  = (float*)alloc((size_t)2 * DIM * 4);

  float* qkvF = (float*)big0;
  float* projf = (float*)big0;
  bf16* y1 = (bf16*)big0;
  float* pbuf = (float*)act_bf;  // FFN2 split-K partials

  const float* e0 = e6f;
  const float* e1 = e6f + DIM;
  const float* e2 = e6f + 2 * DIM;
  const float* e3 = e6f + 3 * DIM;
  const float* e4 = e6f + 4 * DIM;
  const float* e5 = e6f + 5 * DIM;

  dim3 tblk(32, 8);
  dim3 ag(SQ / 64, NHEADS);

  prep_small_kernel<<<(6 * DIM + 255) / 256, 256, 0, stream>>>(
      modv, e, e6f, sa_qb, sa_kb, sa_vb, qkvB, ca_kb, ca_vb, kvB, ca_kib, ca_vib, kivB);

  // xs = LN(x)*(1+e1)+e0
  ln_mod_kernel<<<SQ, 256, 0, stream>>>(x, e1, e0, 1, act_bf);

  // ---- self attention: batched QKV ----
  transpose_w3_kernel<<<dim3(48, 48, 3), tblk, 0, stream>>>(sa_qw, sa_kw, sa_vw, wbig, DIM, DIM);
  gemm_db_kernel<128><<<dim3(3 * DIM / 128, SQ / 128), 256, 0, stream>>>(
      act_bf, wbig, qkvB, nullptr, nullptr, qkvF, nullptr, SQ, 3 * DIM, DIM, 0, 1);
  rms_rope_multi_kernel<<<dim3(SQ, 3), 256, 0, stream>>>(
      qkvF, 3 * DIM, 3, sa_nq, sa_nk, 2, 2, 0, freqs, q_bf, k_bf, v_bf);

  attn_kernel<<<ag, 256, 0, stream>>>(q_bf, k_bf, v_bf, nullptr, act_bf, SQ, 0);

  // x = x + (attn @ sa_ow + sa_ob) * e2
  transpose_w3_kernel<<<dim3(48, 48, 1), tblk, 0, stream>>>(sa_ow, nullptr, nullptr, wsm, DIM, DIM);
  gemm_db_kernel<64><<<dim3(DIM / 128, SQ / 64), 256, 0, stream>>>(
      act_bf, wsm, sa_ob, e2, x, xcur, nullptr, SQ, DIM, DIM, 0, 1);

  // ---- cross attention ----
  ln_mod_kernel<<<SQ, 256, 0, stream>>>(xcur, norm3w, norm3b, 0, act_bf);

  transpose_w3_kernel<<<dim3(48, 48, 1), tblk, 0, stream>>>(ca_qw, nullptr, nullptr, wsm, DIM, DIM);
  gemm_db_kernel<64><<<dim3(DIM / 128, SQ / 64), 256, 0, stream>>>(
      act_bf, wsm, ca_qb, nullptr, nullptr, projf, nullptr, SQ, DIM, DIM, 0, 1);
  rms_rope_multi_kernel<<<dim3(SQ, 1), 256, 0, stream>>>(
      projf, DIM, 1, ca_nq, nullptr, 1, 0, 0, freqs, q_bf, nullptr, nullptr);

  prep_ctx_kernel<<<(T5 * DIM + 255) / 256, 256, 0, stream>>>(ctx, ctxt_bf, ctxi_bf);

  // txt K||V batched (M=512, N=3072)
  transpose_w3_kernel<<<dim3(48, 48, 2), tblk, 0, stream>>>(ca_kw, ca_vw, nullptr, wsm, DIM, DIM);
  gemm_db_kernel<64><<<dim3(2 * DIM / 128, T5 / 64), 256, 0, stream>>>(
      ctxt_bf, wsm, kvB, nullptr, nullptr, ctxkvF, nullptr, T5, 2 * DIM, DIM, 0, 1);
  rms_rope_multi_kernel<<<dim3(T5, 2), 256, 0, stream>>>(
      ctxkvF, 2 * DIM, 2, ca_nk, nullptr, 1, 0, 0, freqs, kt_bf, vt_bf, nullptr);

  // img KI||VI batched (M=384 padded, N=3072)
  transpose_w3_kernel<<<dim3(48, 48, 2), tblk, 0, stream>>>(ca_kiw, ca_viw, nullptr, wsm, DIM, DIM);
  gemm_db_kernel<64><<<dim3(2 * DIM / 128, IMGP / 64), 256, 0, stream>>>(
      ctxi_bf, wsm, kivB, nullptr, nullptr, ctxkivF, nullptr, IMGP, 2 * DIM, DIM, 0, 1);
  rms_rope_multi_kernel<<<dim3(IMGP, 2), 256, 0, stream>>>(
      ctxkivF, 2 * DIM, 2, ca_nki, nullptr, 1, 0, 0, freqs, ki_bf, vi_bf, nullptr);

  attn_kernel<<<ag, 256, 0, stream>>>(q_bf, kt_bf, vt_bf, projf, nullptr, T5, 1);
  attn_kernel<<<ag, 256, 0, stream>>>(q_bf, ki_bf, vi_bf, projf, nullptr, IMG, 2);
  cast_f32_bf16_kernel<<<(SQ * DIM + 255) / 256, 256, 0, stream>>>(projf, act_bf, SQ * DIM);

  // x = x + attn2 @ ca_ow + ca_ob
  transpose_w3_kernel<<<dim3(48, 48, 1), tblk, 0, stream>>>(ca_ow, nullptr, nullptr, wsm, DIM, DIM);
  gemm_db_kernel<64><<<dim3(DIM / 128, SQ / 64), 256, 0, stream>>>(
      act_bf, wsm, ca_ob, nullptr, xcur, xcur, nullptr, SQ, DIM, DIM, 0, 1);

  // ---- FFN ----
  ln_mod_kernel<<<SQ, 256, 0, stream>>>(xcur, e4, e3, 1, act_bf);

  transpose_w3_kernel<<<dim3(FFN / 32, 48, 1), tblk, 0, stream>>>(ffn_w1, nullptr, nullptr, wbig, DIM, FFN);
  gemm_db_kernel<128><<<dim3(FFN / 128, SQ / 128), 256, 0, stream>>>(
      act_bf, wbig, ffn_b1, nullptr, nullptr, nullptr, y1, SQ, FFN, DIM, 1, 1);

  transpose_w3_kernel<<<dim3(48, FFN / 32, 1), tblk, 0, stream>>>(ffn_w2, nullptr, nullptr, wbig, FFN, DIM);
  // split-K=2 partials into pbuf (overlaid on dead act/q/k/v region)
  gemm_db_kernel<128><<<dim3(DIM / 128, SQ / 128, 2), 256, 0, stream>>>(
      y1, wbig, nullptr, nullptr, nullptr, pbuf, nullptr, SQ, DIM, FFN, 0, 2);
  ffn2_reduce_kernel<<<(SQ * DIM + 255) / 256, 256, 0, stream>>>(
      pbuf, ffn_b2, e5, xcur, (float*)d_out);
}